// Round 5
// baseline (92.670 us; speedup 1.0000x reference)
//
#include <hip/hip_runtime.h>

// Per-element MLP 1->32->(32x32)x9->1, leaky relu.
// R10: R9 (LDS weights + rolled layer loop, (256,3), no spill) won: steady
// <40us, harness 89.9. Remaining cost: per-layer serial latency - two
// acc-CHAINED 32x32x16 MFMAs (~170cyc/layer critical path). Switch to
// v_mfma_f32_16x16x32_f16: K=32 in ONE instruction -> the 32x32 output per
// chain-layer becomes 4 fully INDEPENDENT 16x16 MFMAs (2 unit-tiles x 2
// batch-halves); serial chain/layer drops to ~60cyc. Layout via verified
// 16x16 C/D map (col=lane&15, row=4g+reg): umap(g,j)=4g+(j&3)+16*(j>>2)
// makes epilogue pk_cvt pairs feed next layer's B fragment directly (no
// shuffles; weight-side LDS prebake absorbs the permutation). Bias in the
// per-tile C operand. Output layer via v_dot2_f32_f16 (4x fewer VALU ops).
// Next-layer weight ds_reads rotated (software pipeline, +16 regs).
// Reg audit ~145/168 at (256,3); LDS 19.1 KiB/block, 3 blocks/CU.
#define NLAYERS 9
#define HID 32
#define SLOPE 0.01f

typedef _Float16 v2h __attribute__((ext_vector_type(2)));
typedef _Float16 v8h __attribute__((ext_vector_type(8)));
typedef float v4f __attribute__((ext_vector_type(4)));

#define NCHAIN 4

union U8 { v8h v; v2h p[4]; };          // B-operand fragment (8 f16 = 4 VGPRs)

__device__ __forceinline__ v2h pk_cvt(float a, float b) {
    return __builtin_bit_cast(v2h, __builtin_amdgcn_cvt_pkrtz(a, b));
}
__device__ __forceinline__ v2h leaky2(v2h t, v2h s) {
    return __builtin_elementwise_max(t, t * s);
}
// k-slot (group g = lane>>4, elem j) -> logical hidden unit; derived from the
// verified 16x16 C/D layout so epilogue pk pairs feed the next B directly.
__device__ __forceinline__ int umap(int g, int j) {
    return 4 * g + (j & 3) + 16 * (j >> 2);
}

__global__ __launch_bounds__(256, 3) void mlp_mfma_kernel(
    const float* __restrict__ x,
    const float* __restrict__ W_in,   // [1,32]
    const float* __restrict__ b_in,   // [32]
    const float* __restrict__ W_hid,  // [9,32,32]  W[l][k_in][n_out]
    const float* __restrict__ b_hid,  // [9,32]
    const float* __restrict__ W_out,  // [32,1]
    const float* __restrict__ b_out,  // [1]
    float* __restrict__ out, int N)
{
    // A-operand fragments, pre-permuted: lane ln=(i | g<<4) of tile t reads
    // 16B contiguous = W[umap(g,j)][16t+i], j=0..7. 64x16B = conflict-free.
    __shared__ __align__(16) _Float16 wA_sh[NLAYERS][2][64][8];  // 18 KiB
    // f32 bias in 16x16 C layout: tile t, entry 4g+r <- b_hid[16t+4g+r]
    __shared__ __align__(64) float bc_sh[NLAYERS][2][16];        // 1.1 KiB

    const int tid = threadIdx.x;
    for (int t = tid; t < NLAYERS * 2 * 64; t += blockDim.x) {
        int l = t >> 7, r = t & 127, tt = (r >> 6) & 1, ln = r & 63;
        int i = ln & 15, g = ln >> 4;
        const float* Wl = W_hid + l * HID * HID;
        v8h w;
#pragma unroll
        for (int j = 0; j < 8; ++j)
            w[j] = (_Float16)Wl[umap(g, j) * HID + 16 * tt + i];
        *(v8h*)&wA_sh[l][tt][ln][0] = w;
    }
    for (int t = tid; t < NLAYERS * HID; t += blockDim.x)
        ((float*)bc_sh)[t] = b_hid[t];   // flat layout matches b_hid exactly
    __syncthreads();

    const int lane = tid & 63;
    const int g    = lane >> 4;     // k-group / C-row group
    const int col  = lane & 15;     // batch column within 16-wide half

    // ---- register-resident io-layer fragments (12 VGPRs) ----
    v2h win2[4], bin2[4], wout2[4];
#pragma unroll
    for (int jj = 0; jj < 4; ++jj) {
        int u0 = umap(g, 2 * jj), u1 = umap(g, 2 * jj + 1);  // u1 == u0+1
        win2[jj]  = v2h{(_Float16)W_in[u0],  (_Float16)W_in[u1]};
        bin2[jj]  = v2h{(_Float16)b_in[u0],  (_Float16)b_in[u1]};
        wout2[jj] = v2h{(_Float16)W_out[u0], (_Float16)W_out[u1]};
    }
    const float bo = b_out[0];
    const v2h slope2 = v2h{(_Float16)SLOPE, (_Float16)SLOPE};

    const int nwaves = (gridDim.x * blockDim.x) >> 6;
    const int wid    = (blockIdx.x * blockDim.x + tid) >> 6;
    const int niter  = (N + NCHAIN * 32 - 1) / (NCHAIN * 32);

    // ---- x prefetch for first iteration (2 cols per lane per chain) ----
    float xc[2 * NCHAIN] = {};
    if (wid < niter) {
#pragma unroll
        for (int c = 0; c < NCHAIN; ++c)
#pragma unroll
            for (int nh = 0; nh < 2; ++nh) {
                int idx = wid * (NCHAIN * 32) + c * 32 + 16 * nh + col;
                xc[2 * c + nh] = (idx < N) ? x[idx] : 0.0f;
            }
    }

    for (int it = wid; it < niter; it += nwaves) {
        // prefetch next iteration's x (hides HBM latency under compute)
        float xn[2 * NCHAIN] = {};
        {
            int nit = it + nwaves;
            if (nit < niter) {
#pragma unroll
                for (int c = 0; c < NCHAIN; ++c)
#pragma unroll
                    for (int nh = 0; nh < 2; ++nh) {
                        int idx = nit * (NCHAIN * 32) + c * 32 + 16 * nh + col;
                        xn[2 * c + nh] = (idx < N) ? x[idx] : 0.0f;
                    }
            }
        }

        // ---- input layer: build B fragments for all chains/halves ----
        U8 f[NCHAIN][2];
#pragma unroll
        for (int c = 0; c < NCHAIN; ++c)
#pragma unroll
            for (int nh = 0; nh < 2; ++nh) {
                _Float16 xh = (_Float16)xc[2 * c + nh];
                v2h x2 = v2h{xh, xh};
#pragma unroll
                for (int jj = 0; jj < 4; ++jj)
                    f[c][nh].p[jj] = leaky2(x2 * win2[jj] + bin2[jj], slope2);
            }

        // ---- 9 hidden layers: REAL loop (no unroll; R6/R7 spill lesson),
        // next-layer weights rotated in ahead of use ----
        v8h wA0 = *(const v8h*)&wA_sh[0][0][lane][0];
        v8h wA1 = *(const v8h*)&wA_sh[0][1][lane][0];
        v4f bc0 = *(const v4f*)&bc_sh[0][0][4 * g];
        v4f bc1 = *(const v4f*)&bc_sh[0][1][4 * g];
#pragma unroll 1
        for (int l = 0; l < NLAYERS; ++l) {
            const int lnx = (l + 1 < NLAYERS) ? l + 1 : l;
            v8h wA0n = *(const v8h*)&wA_sh[lnx][0][lane][0];
            v8h wA1n = *(const v8h*)&wA_sh[lnx][1][lane][0];
            v4f bc0n = *(const v4f*)&bc_sh[lnx][0][4 * g];
            v4f bc1n = *(const v4f*)&bc_sh[lnx][1][4 * g];
            // chains in groups of 2: 8 fully independent MFMAs in flight,
            // 32 acc regs live; K=32 done in one instruction -> no acc chain.
#pragma unroll
            for (int gr = 0; gr < NCHAIN / 2; ++gr) {
                const int c0 = 2 * gr, c1 = 2 * gr + 1;
                v4f a0t0h0 = __builtin_amdgcn_mfma_f32_16x16x32_f16(wA0, f[c0][0].v, bc0, 0, 0, 0);
                v4f a0t0h1 = __builtin_amdgcn_mfma_f32_16x16x32_f16(wA0, f[c0][1].v, bc0, 0, 0, 0);
                v4f a0t1h0 = __builtin_amdgcn_mfma_f32_16x16x32_f16(wA1, f[c0][0].v, bc1, 0, 0, 0);
                v4f a0t1h1 = __builtin_amdgcn_mfma_f32_16x16x32_f16(wA1, f[c0][1].v, bc1, 0, 0, 0);
                v4f a1t0h0 = __builtin_amdgcn_mfma_f32_16x16x32_f16(wA0, f[c1][0].v, bc0, 0, 0, 0);
                v4f a1t0h1 = __builtin_amdgcn_mfma_f32_16x16x32_f16(wA0, f[c1][1].v, bc0, 0, 0, 0);
                v4f a1t1h0 = __builtin_amdgcn_mfma_f32_16x16x32_f16(wA1, f[c1][0].v, bc1, 0, 0, 0);
                v4f a1t1h1 = __builtin_amdgcn_mfma_f32_16x16x32_f16(wA1, f[c1][1].v, bc1, 0, 0, 0);
                // epilogue: pk pairs land exactly in next-layer B slot order
                f[c0][0].p[0] = leaky2(pk_cvt(a0t0h0[0], a0t0h0[1]), slope2);
                f[c0][0].p[1] = leaky2(pk_cvt(a0t0h0[2], a0t0h0[3]), slope2);
                f[c0][0].p[2] = leaky2(pk_cvt(a0t1h0[0], a0t1h0[1]), slope2);
                f[c0][0].p[3] = leaky2(pk_cvt(a0t1h0[2], a0t1h0[3]), slope2);
                f[c0][1].p[0] = leaky2(pk_cvt(a0t0h1[0], a0t0h1[1]), slope2);
                f[c0][1].p[1] = leaky2(pk_cvt(a0t0h1[2], a0t0h1[3]), slope2);
                f[c0][1].p[2] = leaky2(pk_cvt(a0t1h1[0], a0t1h1[1]), slope2);
                f[c0][1].p[3] = leaky2(pk_cvt(a0t1h1[2], a0t1h1[3]), slope2);
                f[c1][0].p[0] = leaky2(pk_cvt(a1t0h0[0], a1t0h0[1]), slope2);
                f[c1][0].p[1] = leaky2(pk_cvt(a1t0h0[2], a1t0h0[3]), slope2);
                f[c1][0].p[2] = leaky2(pk_cvt(a1t1h0[0], a1t1h0[1]), slope2);
                f[c1][0].p[3] = leaky2(pk_cvt(a1t1h0[2], a1t1h0[3]), slope2);
                f[c1][1].p[0] = leaky2(pk_cvt(a1t0h1[0], a1t0h1[1]), slope2);
                f[c1][1].p[1] = leaky2(pk_cvt(a1t0h1[2], a1t0h1[3]), slope2);
                f[c1][1].p[2] = leaky2(pk_cvt(a1t1h1[0], a1t1h1[1]), slope2);
                f[c1][1].p[3] = leaky2(pk_cvt(a1t1h1[2], a1t1h1[3]), slope2);
            }
            wA0 = wA0n; wA1 = wA1n; bc0 = bc0n; bc1 = bc1n;
        }

        // ---- output layer: v_dot2_f32_f16, then 4-group reduce ----
#pragma unroll
        for (int c = 0; c < NCHAIN; ++c)
#pragma unroll
            for (int nh = 0; nh < 2; ++nh) {
                float p = 0.0f;
#pragma unroll
                for (int jj = 0; jj < 4; ++jj)
                    p = __builtin_amdgcn_fdot2(f[c][nh].p[jj], wout2[jj], p, false);
                p += __shfl_xor(p, 16, 64);
                p += __shfl_xor(p, 32, 64);   // sum over all 4 k-groups
                float o = p + bo;
                int idx = it * (NCHAIN * 32) + c * 32 + 16 * nh + col;
                // each (c,nh) stored by exactly one 16-lane group (coalesced)
                if (g == 2 * (c & 1) + nh && idx < N) out[idx] = o;
            }

#pragma unroll
        for (int q = 0; q < 2 * NCHAIN; ++q) xc[q] = xn[q];
    }
}

extern "C" void kernel_launch(void* const* d_in, const int* in_sizes, int n_in,
                              void* d_out, int out_size, void* d_ws, size_t ws_size,
                              hipStream_t stream) {
    const float* x     = (const float*)d_in[0];
    const float* W_in  = (const float*)d_in[1];
    const float* b_in  = (const float*)d_in[2];
    const float* W_hid = (const float*)d_in[3];
    const float* b_hid = (const float*)d_in[4];
    const float* W_out = (const float*)d_in[5];
    const float* b_out = (const float*)d_in[6];
    float* out = (float*)d_out;

    int N = in_sizes[0];
    // 768 blocks x 4 waves = 3072 waves = 3 waves/SIMD (168-reg budget,
    // ~145 live with rolled layer loop; 19.1 KiB LDS x 3 = 57.4 KiB/CU).
    // niter = 8192 -> 2-3 iterations/wave.
    dim3 block(256);
    dim3 grid(768);
    mlp_mfma_kernel<<<grid, block, 0, stream>>>(x, W_in, b_in, W_hid, b_hid,
                                                W_out, b_out, out, N);
}